// Round 5
// baseline (1202.552 us; speedup 1.0000x reference)
//
#include <hip/hip_runtime.h>

// RNN scan: h <- tanh(x_t @ W_ih^T + h @ W_hh^T + b), 2048 steps, 1 block/batch.
// v4: 1024 threads = 64 rowgroups x 16 colgroups (4 waves/SIMD, was 2).
// Thread (g,c) owns rows 2g..2g+1, cols 8c..8c+7 of Whh (8 VGPRs).
// Reduce: round1 xor1 scatter (2 cndmask) then PURE all-reduce xor2/ror4/ror8
// (no selects) -> even c lanes hold row 2g, odd hold 2g+1; writer gate c<2.
// Bias folded into xwbuf during compute_xw. x-projection stays on the MFMA
// pipe (waves 0-7, 12 MFMA/wave/chunk, bf16 hi/lo 3-pass), staging on t<512.

#define BATCH 256
#define SEQ   2048
#define HID   128
#define CH    16
#define NCHUNK (SEQ / CH)

typedef __attribute__((ext_vector_type(8))) short bf16x8;
typedef __attribute__((ext_vector_type(4))) float f32x4;

// DPP ctrl: quad_perm[1,0,3,2]=0xB1 (xor1), quad_perm[2,3,0,1]=0x4E (xor2),
// row_ror:4=0x124, row_ror:8=0x128 (rows of 16 lanes on gfx9+)
template <int CTRL>
__device__ __forceinline__ float dpp_movf(float x) {
    return __int_as_float(__builtin_amdgcn_mov_dpp(__float_as_int(x), CTRL, 0xF, 0xF, true));
}

__device__ __forceinline__ float tanh_fast(float x) {
    x = fminf(fmaxf(x, -12.0f), 12.0f);
    float e = __expf(2.0f * x);
    return 1.0f - __fdividef(2.0f, e + 1.0f);
}

// split float -> (hi, lo) bf16 pair capturing ~16 mantissa bits
__device__ __forceinline__ void bf16_split(float v, short& hi, short& lo) {
    unsigned u = __float_as_uint(v);
    unsigned hb = (u + 0x8000u) & 0xFFFF0000u;   // round-to-nearest-ish hi
    float hf = __uint_as_float(hb);
    float r = v - hf;
    unsigned ru = __float_as_uint(r);
    hi = (short)(hb >> 16);
    lo = (short)((ru + 0x8000u) >> 16);
}

__global__ __launch_bounds__(1024, 4) void rnn_scan_kernel(
    const float* __restrict__ x,    // [B, S, 128]
    const float* __restrict__ Wih,  // [128, 128]
    const float* __restrict__ bih,  // [128]
    const float* __restrict__ Whh,  // [128, 128]
    const float* __restrict__ bhh,  // [128]
    float* __restrict__ out)        // [B, 128]
{
    const int b = blockIdx.x;
    const int t = threadIdx.x;
    const int g = t >> 4;          // row group: rows 2g..2g+1
    const int c = t & 15;          // col group: cols 8c..8c+7 (of h)
    const int colbase = c << 3;
    const int rowbase = g << 1;
    const int lane = t & 63;
    const int w = t >> 6;          // wave 0..15

    __shared__ __align__(16) ushort xbf[2][2][CH * HID];  // [buf][hi/lo] bf16 x, swizzled (16 KB)
    __shared__ __align__(16) float  xwbuf[2][CH * HID];   // precomputed xw + bias (16 KB)
    __shared__ __align__(16) float  hbuf[2][192];         // padded: p(r) = r + 4*(r>>3)

    // --- Whh tile into registers: 2 rows x 8 cols = 8 VGPRs ---
    float4 wh[2][2];
#pragma unroll
    for (int r = 0; r < 2; ++r) {
        const float* ph = Whh + (rowbase + r) * HID + colbase;
        wh[r][0] = *(const float4*)(ph);
        wh[r][1] = *(const float4*)(ph + 4);
    }

    // --- Wih B-fragments (bf16 hi/lo) for waves 0-7 only ---
    // canonical 16x16x32 B layout: lane holds B[k=(lane>>4)*8+j][col=lane&15].
    // B[k][col] = Wih[col_global][k] -> 8 k-contiguous floats per frag.
    const int bcol = ((w & 7) << 4) + (lane & 15);  // output col (h row), waves 0-7
    bf16x8 bhi[4], blo[4];
    float biasv = 0.0f;
    if (w < 8) {
        biasv = bih[bcol] + bhh[bcol];
#pragma unroll
        for (int kk = 0; kk < 4; ++kk) {
            const float* src = Wih + bcol * HID + kk * 32 + ((lane >> 4) << 3);
            float4 u0 = *(const float4*)(src);
            float4 u1 = *(const float4*)(src + 4);
            short hh, ll;
            bf16_split(u0.x, hh, ll); bhi[kk][0] = hh; blo[kk][0] = ll;
            bf16_split(u0.y, hh, ll); bhi[kk][1] = hh; blo[kk][1] = ll;
            bf16_split(u0.z, hh, ll); bhi[kk][2] = hh; blo[kk][2] = ll;
            bf16_split(u0.w, hh, ll); bhi[kk][3] = hh; blo[kk][3] = ll;
            bf16_split(u1.x, hh, ll); bhi[kk][4] = hh; blo[kk][4] = ll;
            bf16_split(u1.y, hh, ll); bhi[kk][5] = hh; blo[kk][5] = ll;
            bf16_split(u1.z, hh, ll); bhi[kk][6] = hh; blo[kk][6] = ll;
            bf16_split(u1.w, hh, ll); bhi[kk][7] = hh; blo[kk][7] = ll;
        }
    }

    // lane ends holding row0 = 2g + (c&1) after the reduce
    const int row0 = rowbase + (c & 1);
    const int hw = row0 + ((row0 >> 3) << 2);        // padded index of row0

    const float* xsrc = x + (size_t)b * (SEQ * HID);

    // stage float4 #idx (of 512) of chunk -> xbf[buf] (bf16 hi/lo, swizzled)
    auto stage_bf16 = [&](float4 q, int buf, int idx) {
        const int srow = idx >> 5;                     // step row 0..15
        const int sw = ((srow << 8) + ((idx & 31) << 3)) ^ ((srow & 7) << 4);
        short h0, l0, h1, l1, h2, l2, h3, l3;
        bf16_split(q.x, h0, l0); bf16_split(q.y, h1, l1);
        bf16_split(q.z, h2, l2); bf16_split(q.w, h3, l3);
        uint2 ph, pl;
        ph.x = (unsigned)(ushort)h0 | ((unsigned)(ushort)h1 << 16);
        ph.y = (unsigned)(ushort)h2 | ((unsigned)(ushort)h3 << 16);
        pl.x = (unsigned)(ushort)l0 | ((unsigned)(ushort)l1 << 16);
        pl.y = (unsigned)(ushort)l2 | ((unsigned)(ushort)l3 << 16);
        *(uint2*)((char*)&xbf[buf][0][0] + sw) = ph;
        *(uint2*)((char*)&xbf[buf][1][0] + sw) = pl;
    };

    // xw(m) = X_chunk(m) @ Wih^T + bias, via 12 MFMA (hi*hi + hi*lo + lo*hi)
    auto compute_xw = [&](int mm) {
        const int buf = mm & 1;
        const int arow = lane & 15;
        const int rowb = (arow << 8) + ((lane >> 4) << 4);   // unswizzled base
        const int swz = (arow & 7) << 4;                     // XOR bits 4-6
        const char* hp = (const char*)&xbf[buf][0][0];
        const char* lp = (const char*)&xbf[buf][1][0];
        f32x4 acc0 = {0.0f, 0.0f, 0.0f, 0.0f};
        f32x4 acc1 = {0.0f, 0.0f, 0.0f, 0.0f};
#pragma unroll
        for (int kk = 0; kk < 4; ++kk) {
            const int off = (rowb + kk * 64) ^ swz;          // XOR after full sum
            bf16x8 ah = *(const bf16x8*)(hp + off);
            bf16x8 al = *(const bf16x8*)(lp + off);
            f32x4& acc = (kk & 1) ? acc1 : acc0;             // 2 independent chains
            acc = __builtin_amdgcn_mfma_f32_16x16x32_bf16(ah, bhi[kk], acc, 0, 0, 0);
            acc = __builtin_amdgcn_mfma_f32_16x16x32_bf16(ah, blo[kk], acc, 0, 0, 0);
            acc = __builtin_amdgcn_mfma_f32_16x16x32_bf16(al, bhi[kk], acc, 0, 0, 0);
        }
        // C/D layout (verified m89): col = lane&15, row = (lane>>4)*4 + r
        float* xw = &xwbuf[buf][0];
        const int crow = (lane >> 4) << 2;
#pragma unroll
        for (int r = 0; r < 4; ++r)
            xw[(crow + r) * HID + bcol] = acc0[r] + acc1[r] + biasv;
    };

    // --- prologue: stage chunks 0,1 (1024 float4 = 2 chunks), zero h, xw(0) ---
    {
        const float4* gp = (const float4*)xsrc;
        stage_bf16(gp[t], t >> 9, t & 511);
    }
    if (t < 192) hbuf[0][t] = 0.0f;
    __syncthreads();
    if (w < 8) compute_xw(0);
    __syncthreads();

    int cur = 0;
    for (int n = 0; n < NCHUNK; ++n) {
        float4 q0;
        const bool pf = (n + 2 < NCHUNK);
        if (pf && t < 512) {
            const float4* gp = (const float4*)(xsrc + (size_t)(n + 2) * (CH * HID));
            q0 = gp[t];
        }
        const float* xwc = &xwbuf[n & 1][0];
#pragma unroll 1
        for (int s = 0; s < CH; ++s) {
            float xwv = xwc[s * HID + row0];          // same-addr lanes broadcast
            const float* hr = &hbuf[cur][12 * c];     // p(8c) = 12c, 16B-aligned
            float4 hv0 = *(const float4*)(hr);
            float4 hv1 = *(const float4*)(hr + 4);

            float a0, a1;
            {
                float acc;
                acc = wh[0][0].x * hv0.x;
                acc = fmaf(wh[0][0].y, hv0.y, acc);
                acc = fmaf(wh[0][0].z, hv0.z, acc);
                acc = fmaf(wh[0][0].w, hv0.w, acc);
                acc = fmaf(wh[0][1].x, hv1.x, acc);
                acc = fmaf(wh[0][1].y, hv1.y, acc);
                acc = fmaf(wh[0][1].z, hv1.z, acc);
                acc = fmaf(wh[0][1].w, hv1.w, acc);
                a0 = acc;
                acc = wh[1][0].x * hv0.x;
                acc = fmaf(wh[1][0].y, hv0.y, acc);
                acc = fmaf(wh[1][0].z, hv0.z, acc);
                acc = fmaf(wh[1][0].w, hv0.w, acc);
                acc = fmaf(wh[1][1].x, hv1.x, acc);
                acc = fmaf(wh[1][1].y, hv1.y, acc);
                acc = fmaf(wh[1][1].z, hv1.z, acc);
                acc = fmaf(wh[1][1].w, hv1.w, acc);
                a1 = acc;
            }

            // --- reduce over the 16-lane col dimension ---
            // round 1: xor1 scatter (even c keep row 2g, odd keep 2g+1)
            const bool b0 = (c & 1) != 0;
            float k0 = b0 ? a1 : a0, s0 = b0 ? a0 : a1;
            float u = k0 + dpp_movf<0xB1>(s0);
            // rounds 2-4: pure all-reduce (parity-preserving): xor2, ror4, ror8
            u += dpp_movf<0x4E>(u);
            u += dpp_movf<0x124>(u);
            u += dpp_movf<0x128>(u);

            float hval = tanh_fast(u + xwv);
            if (c < 2) {  // exactly one writer per row (c=0 -> 2g, c=1 -> 2g+1)
                hbuf[cur ^ 1][hw] = hval;
            }

            // off-critical-path work, overlapped with other waves' VALU:
            if (s == 0 && n + 1 < NCHUNK && w < 8) compute_xw(n + 1);
            if (s == CH - 1 && pf && t < 512) stage_bf16(q0, n & 1, t);

            __syncthreads();
            cur ^= 1;
        }
    }
    // cur == 0 after 2048 toggles; hbuf[0] holds h_final (padded layout)
    if (t < HID) out[(size_t)b * HID + t] = hbuf[cur][t + ((t >> 3) << 2)];
}

extern "C" void kernel_launch(void* const* d_in, const int* in_sizes, int n_in,
                              void* d_out, int out_size, void* d_ws, size_t ws_size,
                              hipStream_t stream) {
    const float* x   = (const float*)d_in[0];
    const float* Wih = (const float*)d_in[1];
    const float* bih = (const float*)d_in[2];
    const float* Whh = (const float*)d_in[3];
    const float* bhh = (const float*)d_in[4];
    float* out = (float*)d_out;

    rnn_scan_kernel<<<BATCH, 1024, 0, stream>>>(x, Wih, bih, Whh, bhh, out);
}

// Round 6
// 1112.702 us; speedup vs baseline: 1.0807x; 1.0807x over previous
//
#include <hip/hip_runtime.h>

// RNN scan: h <- tanh(x_t @ W_ih^T + h @ W_hh^T + b), 2048 steps, 1 block/batch.
// v5 = v3.2 structure (512 thr, 2 waves/SIMD — best measured) with per-wave
// issue cuts only (v4 showed we are SIMD-issue-bound; +waves = +redundant issue):
//  - v_pk_fma_f32 via float2 col-pair packing: 32 fmac -> 16 pk_fma + 4 hadd
//  - 16-step inner loop fully unrolled: cur static (CH even), LDS addrs become
//    base+immediate, no per-step loop/cur/addr overhead
//  - bias folded into xwbuf at compute_xw time (proven in v4)
//  - ungated broadcast xw read (same-address lanes conflict-free, proven in v4)
//  - tanh: single mul into exp2-based exp, clamp kept
// x-projection stays on the MFMA pipe (12 MFMA/wave/chunk, bf16 hi/lo 3-pass,
// double-buffered, off critical path at s==0). Reduce identical to v3.2.

#define BATCH 256
#define SEQ   2048
#define HID   128
#define CH    16
#define NCHUNK (SEQ / CH)

typedef __attribute__((ext_vector_type(8))) short bf16x8;
typedef __attribute__((ext_vector_type(4))) float f32x4;
typedef __attribute__((ext_vector_type(2))) float f32x2;

// DPP ctrl: quad_perm[1,0,3,2]=0xB1 (xor1), quad_perm[2,3,0,1]=0x4E (xor2),
// row_ror:4=0x124, row_ror:8=0x128 (rows of 16 lanes on gfx9+)
template <int CTRL>
__device__ __forceinline__ float dpp_movf(float x) {
    return __int_as_float(__builtin_amdgcn_mov_dpp(__float_as_int(x), CTRL, 0xF, 0xF, true));
}

__device__ __forceinline__ float tanh_fast(float x) {
    x = fminf(fmaxf(x, -12.0f), 12.0f);
    float e = __expf(2.0f * x);                 // v_mul + v_exp after fast-math
    return 1.0f - __fdividef(2.0f, e + 1.0f);   // add + rcp + mul + sub
}

// split float -> (hi, lo) bf16 pair capturing ~16 mantissa bits
__device__ __forceinline__ void bf16_split(float v, short& hi, short& lo) {
    unsigned u = __float_as_uint(v);
    unsigned hb = (u + 0x8000u) & 0xFFFF0000u;   // round-to-nearest-ish hi
    float hf = __uint_as_float(hb);
    float r = v - hf;
    unsigned ru = __float_as_uint(r);
    hi = (short)(hb >> 16);
    lo = (short)((ru + 0x8000u) >> 16);
}

__global__ __launch_bounds__(512, 2) void rnn_scan_kernel(
    const float* __restrict__ x,    // [B, S, 128]
    const float* __restrict__ Wih,  // [128, 128]
    const float* __restrict__ bih,  // [128]
    const float* __restrict__ Whh,  // [128, 128]
    const float* __restrict__ bhh,  // [128]
    float* __restrict__ out)        // [B, 128]
{
    const int b = blockIdx.x;
    const int t = threadIdx.x;
    const int g = t >> 4;          // row group: rows 4g..4g+3
    const int c = t & 15;          // col group: cols 8c..8c+7 (of h)
    const int colbase = c << 3;
    const int rowbase = g << 2;
    const int lane = t & 63;
    const int w = t >> 6;          // wave 0..7

    __shared__ __align__(16) ushort xbf[2][2][CH * HID];  // [buf][hi/lo] bf16 x, swizzled (16 KB)
    __shared__ __align__(16) float  xwbuf[2][CH * HID];   // precomputed xw + bias (16 KB)
    __shared__ __align__(16) float  hbuf[2][192];         // padded: p(r) = r + 4*(r>>3)

    // --- Whh tile into registers: 4 rows x 4 col-pairs (float2) = 32 VGPRs ---
    f32x2 wh[4][4];
#pragma unroll
    for (int r = 0; r < 4; ++r) {
        const float* ph = Whh + (rowbase + r) * HID + colbase;
        float4 u0 = *(const float4*)(ph);
        float4 u1 = *(const float4*)(ph + 4);
        wh[r][0] = f32x2{u0.x, u0.y};
        wh[r][1] = f32x2{u0.z, u0.w};
        wh[r][2] = f32x2{u1.x, u1.y};
        wh[r][3] = f32x2{u1.z, u1.w};
    }

    // --- Wih B-fragments (bf16 hi/lo), canonical 16x16x32 B layout:
    // lane holds B[k=(lane>>4)*8+j][col=lane&15], tile col offset 16w.
    // B[k][col] = Wih[col_global][k] -> 8 k-contiguous floats per frag. ---
    const int bcol = (w << 4) + (lane & 15);   // global output col (h row)
    const float biasv = bih[bcol] + bhh[bcol];
    bf16x8 bhi[4], blo[4];
#pragma unroll
    for (int kk = 0; kk < 4; ++kk) {
        const float* src = Wih + bcol * HID + kk * 32 + ((lane >> 4) << 3);
        float4 u0 = *(const float4*)(src);
        float4 u1 = *(const float4*)(src + 4);
        short hh, ll;
        bf16_split(u0.x, hh, ll); bhi[kk][0] = hh; blo[kk][0] = ll;
        bf16_split(u0.y, hh, ll); bhi[kk][1] = hh; blo[kk][1] = ll;
        bf16_split(u0.z, hh, ll); bhi[kk][2] = hh; blo[kk][2] = ll;
        bf16_split(u0.w, hh, ll); bhi[kk][3] = hh; blo[kk][3] = ll;
        bf16_split(u1.x, hh, ll); bhi[kk][4] = hh; blo[kk][4] = ll;
        bf16_split(u1.y, hh, ll); bhi[kk][5] = hh; blo[kk][5] = ll;
        bf16_split(u1.z, hh, ll); bhi[kk][6] = hh; blo[kk][6] = ll;
        bf16_split(u1.w, hh, ll); bhi[kk][7] = hh; blo[kk][7] = ll;
    }

    // reduce-scatter row assignment: lane class m = c&3 ends with row 4g + o(m)
    const int m = c & 3;
    const int o = ((m & 1) << 1) | ((m >> 1) & 1);   // 0,2,1,3 for m=0..3
    const int row0 = rowbase + o;
    const int hw = row0 + ((row0 >> 3) << 2);        // padded index of row0

    const float* xsrc = x + (size_t)b * (SEQ * HID);

    // stage one chunk of x as bf16 hi/lo into xbf[buf] (swizzled rows)
    auto stage_bf16 = [&](float4 q, int buf) {
        const int srow = t >> 5;                       // step row 0..15
        const int sw = ((srow << 8) + ((t & 31) << 3)) ^ ((srow & 7) << 4);
        short h0, l0, h1, l1, h2, l2, h3, l3;
        bf16_split(q.x, h0, l0); bf16_split(q.y, h1, l1);
        bf16_split(q.z, h2, l2); bf16_split(q.w, h3, l3);
        uint2 ph, pl;
        ph.x = (unsigned)(ushort)h0 | ((unsigned)(ushort)h1 << 16);
        ph.y = (unsigned)(ushort)h2 | ((unsigned)(ushort)h3 << 16);
        pl.x = (unsigned)(ushort)l0 | ((unsigned)(ushort)l1 << 16);
        pl.y = (unsigned)(ushort)l2 | ((unsigned)(ushort)l3 << 16);
        *(uint2*)((char*)&xbf[buf][0][0] + sw) = ph;
        *(uint2*)((char*)&xbf[buf][1][0] + sw) = pl;
    };

    // xw(m) = X_chunk(m) @ Wih^T + bias, via 12 MFMA (hi*hi + hi*lo + lo*hi)
    auto compute_xw = [&](int mm) {
        const int buf = mm & 1;
        const int arow = lane & 15;
        const int rowb = (arow << 8) + ((lane >> 4) << 4);   // unswizzled base
        const int swz = (arow & 7) << 4;                     // XOR bits 4-6
        const char* hp = (const char*)&xbf[buf][0][0];
        const char* lp = (const char*)&xbf[buf][1][0];
        f32x4 acc0 = {0.0f, 0.0f, 0.0f, 0.0f};
        f32x4 acc1 = {0.0f, 0.0f, 0.0f, 0.0f};
#pragma unroll
        for (int kk = 0; kk < 4; ++kk) {
            const int off = (rowb + kk * 64) ^ swz;          // XOR after full sum
            bf16x8 ah = *(const bf16x8*)(hp + off);
            bf16x8 al = *(const bf16x8*)(lp + off);
            f32x4& acc = (kk & 1) ? acc1 : acc0;             // 2 independent chains
            acc = __builtin_amdgcn_mfma_f32_16x16x32_bf16(ah, bhi[kk], acc, 0, 0, 0);
            acc = __builtin_amdgcn_mfma_f32_16x16x32_bf16(ah, blo[kk], acc, 0, 0, 0);
            acc = __builtin_amdgcn_mfma_f32_16x16x32_bf16(al, bhi[kk], acc, 0, 0, 0);
        }
        // C/D layout (verified m89): col = lane&15, row = (lane>>4)*4 + r
        float* xw = &xwbuf[buf][0];
        const int crow = (lane >> 4) << 2;
#pragma unroll
        for (int r = 0; r < 4; ++r)
            xw[(crow + r) * HID + bcol] = acc0[r] + acc1[r] + biasv;
    };

    // --- prologue: stage chunks 0,1 (bf16), zero h, xw(0) ---
    {
        const float4* gp = (const float4*)xsrc;
        float4 a0 = gp[t];
        float4 a1 = gp[512 + t];
        stage_bf16(a0, 0);
        stage_bf16(a1, 1);
    }
    if (t < 192) hbuf[0][t] = 0.0f;
    __syncthreads();
    compute_xw(0);
    __syncthreads();

    for (int n = 0; n < NCHUNK; ++n) {
        float4 q0;
        const bool pf = (n + 2 < NCHUNK);
        if (pf) {
            const float4* gp = (const float4*)(xsrc + (size_t)(n + 2) * (CH * HID));
            q0 = gp[t];
        }
        const float* xwc = &xwbuf[n & 1][0] + row0;   // per-step +HID immediate
        const float* h0p = &hbuf[0][12 * c];
        const float* h1p = &hbuf[1][12 * c];
        // fully unrolled: cur is statically s&1 (CH even -> cur==0 at chunk start)
#pragma unroll
        for (int s = 0; s < CH; ++s) {
            float xwv = xwc[s * HID];                 // same-addr lanes broadcast
            const float* hr = (s & 1) ? h1p : h0p;
            float4 hv0 = *(const float4*)(hr);
            float4 hv1 = *(const float4*)(hr + 4);
            f32x2 hp0 = {hv0.x, hv0.y};
            f32x2 hp1 = {hv0.z, hv0.w};
            f32x2 hp2 = {hv1.x, hv1.y};
            f32x2 hp3 = {hv1.z, hv1.w};

            float a[4];
#pragma unroll
            for (int r = 0; r < 4; ++r) {
                f32x2 acc = wh[r][0] * hp0;                       // v_pk_mul_f32
                acc = __builtin_elementwise_fma(wh[r][1], hp1, acc);  // v_pk_fma_f32
                acc = __builtin_elementwise_fma(wh[r][2], hp2, acc);
                acc = __builtin_elementwise_fma(wh[r][3], hp3, acc);
                a[r] = acc.x + acc.y;                             // horizontal fold
            }

            // --- DPP reduce-scatter over the 16-lane col dimension (as v3.2) ---
            const bool b0 = (c & 1) != 0;
            const bool b1 = (c & 2) != 0;
            float k0 = b0 ? a[2] : a[0], s0 = b0 ? a[0] : a[2];
            float k1 = b0 ? a[3] : a[1], s1 = b0 ? a[1] : a[3];
            float t0 = k0 + dpp_movf<0xB1>(s0);
            float t1 = k1 + dpp_movf<0xB1>(s1);
            float k2 = b1 ? t1 : t0, s2 = b1 ? t0 : t1;
            float u = k2 + dpp_movf<0x4E>(s2);
            u += dpp_movf<0x124>(u);
            u += dpp_movf<0x128>(u);

            float hval = tanh_fast(u + xwv);
            if (c < 4) {  // lanes c>=4 hold duplicates
                hbuf[(s & 1) ^ 1][hw] = hval;
            }

            // off-critical-path work, overlapped with other waves' VALU:
            if (s == 0 && n + 1 < NCHUNK) compute_xw(n + 1);
            if (s == CH - 1 && pf) stage_bf16(q0, n & 1);  // x(n+2) -> xbf[(n+2)&1]

            __syncthreads();
        }
    }
    // after even # of toggles, hbuf[0] holds h_final (padded layout)
    if (t < HID) out[(size_t)b * HID + t] = hbuf[0][t + ((t >> 3) << 2)];
}

extern "C" void kernel_launch(void* const* d_in, const int* in_sizes, int n_in,
                              void* d_out, int out_size, void* d_ws, size_t ws_size,
                              hipStream_t stream) {
    const float* x   = (const float*)d_in[0];
    const float* Wih = (const float*)d_in[1];
    const float* bih = (const float*)d_in[2];
    const float* Whh = (const float*)d_in[3];
    const float* bhh = (const float*)d_in[4];
    float* out = (float*)d_out;

    rnn_scan_kernel<<<BATCH, 512, 0, stream>>>(x, Wih, bih, Whh, bhh, out);
}